// Round 4
// baseline (350.189 us; speedup 1.0000x reference)
//
#include <hip/hip_runtime.h>

// ---------- types ----------
typedef _Float16 f16x8 __attribute__((ext_vector_type(8)));
typedef _Float16 f16x4 __attribute__((ext_vector_type(4)));
typedef unsigned short u16x8 __attribute__((ext_vector_type(8)));
typedef unsigned short u16x4 __attribute__((ext_vector_type(4)));
typedef float f32x4 __attribute__((ext_vector_type(4)));

#define GLOAD_LDS16(GP, LP)                                                        \
  __builtin_amdgcn_global_load_lds((const __attribute__((address_space(1))) void*)(GP), \
                                   (__attribute__((address_space(3))) void*)(LP), 16, 0, 0)

__device__ __forceinline__ unsigned int pkh(float a, float b) {
  return __builtin_bit_cast(unsigned int, __builtin_amdgcn_cvt_pkrtz(a, b));
}
__device__ __forceinline__ f16x8 ldfragh(const unsigned short* p) {
  return __builtin_bit_cast(f16x8, *(const u16x8*)p);
}
__device__ __forceinline__ f16x4 ldfragh4(const unsigned short* p) {
  return __builtin_bit_cast(f16x4, *(const u16x4*)p);
}
__device__ __forceinline__ f32x4 mfma32h(f16x8 a, f16x8 b, f32x4 c) {
  return __builtin_amdgcn_mfma_f32_16x16x32_f16(a, b, c, 0, 0, 0);
}
__device__ __forceinline__ f32x4 mfma16h(f16x4 a, f16x4 b, f32x4 c) {
  return __builtin_amdgcn_mfma_f32_16x16x16f16(a, b, c, 0, 0, 0);
}

// ---------- problem constants ----------
// B=8 P=4 N=512 C=768 H=12 HD=64; M = B*P*N = 16384
#define MTOK   16384
#define CDIM   768
#define C3     2304
#define C2     1536
#define NX     12582912   // M*C
#define NQW    1769472    // 3C*C
#define NPW    589824     // C*C

#define QSCALE_LOG2E 0.1803368801111204f

// ws offsets (bytes)
#define XB_OFF    0ul
#define WQKV_OFF  25165824ul
#define WPROJ_OFF 28704768ul
#define QK_OFF    29884416ul
#define VT_OFF    80216064ul

// ---------- kernel 1: fp32 -> f16 convert (+ fold SCALE*log2e into Wq rows) ----------
__global__ __launch_bounds__(256) void convert_kernel(
    const float* __restrict__ x, const float* __restrict__ wqkv,
    const float* __restrict__ wproj, unsigned short* __restrict__ xb,
    unsigned short* __restrict__ wqkvb, unsigned short* __restrict__ wprojb) {
  const int NX4 = NX / 4, NQ4 = NQW / 4, NP4 = NPW / 4;
  const int total = NX4 + NQ4 + NP4;
  for (int i = blockIdx.x * 256 + threadIdx.x; i < total; i += gridDim.x * 256) {
    const float4* src; unsigned short* dst; float scale = 1.f; int j;
    if (i < NX4) { src = (const float4*)x; dst = xb; j = i; }
    else if (i < NX4 + NQ4) {
      j = i - NX4; src = (const float4*)wqkv; dst = wqkvb;
      int d = (j * 4) / CDIM; if (d < CDIM) scale = QSCALE_LOG2E;
    } else { j = i - NX4 - NQ4; src = (const float4*)wproj; dst = wprojb; }
    float4 v = src[j];
    uint2 pk; pk.x = pkh(v.x * scale, v.y * scale); pk.y = pkh(v.z * scale, v.w * scale);
    *(uint2*)(dst + (long)j * 4) = pk;
  }
}

// ---------- GEMM (B^T input), 256x256 tile, BK=64, m201-style 4-phase schedule ----
// R4 = R3 (audited race-free; vmcnt ledger re-verified) + hardening:
//  (1) sched_barrier(0) after every inline-asm waitcnt (rule #18: hipcc hoists
//      register-only MFMA past asm lgkmcnt despite "memory" clobber);
//  (2) builtin s_barrier bracketed by compiler memory fences (keeps LLVM's
//      convergence modeling vs. one opaque asm);
//  (3) #pragma unroll 2 on the K-tile loop (static buffer parity, ~6x less code).
// Structure: 8 waves = 2M x 4N; wave tile 128x64, interleaved m-halves. Per K-tile
// (BK=64): 4 phases x 16 MFMA (quadrant = (mh,nh)); ds_reads/phase 12/4/8/0.
// LDS: dbuf x {A,B} x 2 halves x (128x64 shorts) = 128 KiB.
// Bank model (fits R7=0, R1/R2=5-6M conflicts): ds_read_b128 services 8
// consecutive lanes/cy; conflict-free iff their 16B slots mod 128B are distinct.
// slot(row,q) = q ^ (row&7); glds dest linear, global src pre-applies involution.
// Stage order: p0 B1(t+1), p1 A1(t+1) [idle buf]; p2 A0(t+2), p3 B0(t+2)
// [current buf, halves already consumed p0/p1]. Gates: vmcnt(8) end-p1 (A1(t)
// landed), vmcnt(6) end-p3 ({A0,B0,B1}(t+1) landed). Tail: t=10 vmcnt(2), t=11
// vmcnt(0) at p1. Never a full drain in steady state.
template <int MODE, int NTN>
__global__ __launch_bounds__(512, 2) void gemm256(
    const unsigned short* __restrict__ A, const unsigned short* __restrict__ B,
    unsigned short* __restrict__ out_hf, unsigned short* __restrict__ out_vT,
    float* __restrict__ out_f32, const float* __restrict__ bias) {
  constexpr int K = 768;
  constexpr int NKT = 12;                        // K / 64
  __shared__ unsigned short As[2][2][128 * 64];  // [buf][half][row*64 + slot^]
  __shared__ unsigned short Bs[2][2][128 * 64];
  const int tid = threadIdx.x;
  const int wave = tid >> 6, lane = tid & 63;
  const int wy = wave >> 2, wx = wave & 3;
  const int l15 = lane & 15, quad = lane >> 4;

  // XCD swizzle: gid&7 = xcd; consecutive g on one XCD share bm -> A-panel L2 hits.
  const int gid = blockIdx.x;
  const int g = gid >> 3;
  const int bn = g % NTN;
  const int bm = (g / NTN) * 8 + (gid & 7);
  const bool swap = (MODE == 2) || (bn < 6);

  f32x4 acc[8][4];
#pragma unroll
  for (int i = 0; i < 8; i++)
#pragma unroll
    for (int j = 0; j < 4; j++) acc[i][j] = f32x4{0.f, 0.f, 0.f, 0.f};

  const unsigned short* Ab = A + (long)bm * 256 * K;
  const unsigned short* Bb = B + (long)bn * 256 * K;

  // staging: half-tile = 128 rows x 64 shorts = 1024 chunks of 16B; 512 thr x 2.
  // phys chunk c -> row = c>>3, slot = c&7, logical q = slot ^ (row&7).
  const int c0 = tid, c1 = tid + 512;
  const long gof0 = (long)(c0 >> 3) * K + (long)(((c0 & 7) ^ ((c0 >> 3) & 7)) * 8);
  const long gof1 = (long)(c1 >> 3) * K + (long)(((c1 & 7) ^ ((c1 >> 3) & 7)) * 8);
  const int s0 = c0 * 8, s1 = c1 * 8;

#define STAGE(DST, GBASE, kt) {                                   \
    const unsigned short* gsrc_ = (GBASE) + (long)(kt) * 64;      \
    GLOAD_LDS16(gsrc_ + gof0, &(DST)[s0]);                        \
    GLOAD_LDS16(gsrc_ + gof1, &(DST)[s1]); }
#define A0G (Ab)
#define A1G (Ab + 128 * K)
#define B0G (Bb)
#define B1G (Bb + 128 * K)
#define BAR() { asm volatile("" ::: "memory"); __builtin_amdgcn_s_barrier(); \
                asm volatile("" ::: "memory"); }
#define SCHED0() __builtin_amdgcn_sched_barrier(0)
#define LGKM0() { asm volatile("s_waitcnt lgkmcnt(0)" ::: "memory"); SCHED0(); }
#define VMW(N)  { asm volatile("s_waitcnt vmcnt(" #N ")" ::: "memory"); SCHED0(); }

  // prologue (issue order matters for vmcnt counting):
  // A0(0), B0(0), B1(0), A1(0), A0(1), B0(1); gate first 3 halves landed.
  STAGE(As[0][0], A0G, 0); STAGE(Bs[0][0], B0G, 0); STAGE(Bs[0][1], B1G, 0);
  STAGE(As[0][1], A1G, 0); STAGE(As[1][0], A0G, 1); STAGE(Bs[1][0], B0G, 1);
  VMW(6);
  BAR();

  // per-thread fragment addressing (conflict-free XOR slots)
  const int sl0 = ((quad)     ^ (l15 & 7)) * 8;   // ks=0
  const int sl1 = ((4 + quad) ^ (l15 & 7)) * 8;   // ks=1
  const int ar = (wy * 64 + l15) * 64;            // A row base within half
  const int br = ((wx & 1) * 64 + l15) * 64;      // B row base within half

#define MFMA_PHASE(MH, NH)                                                   \
  __builtin_amdgcn_s_setprio(1);                                             \
  if (swap) {                                                                \
    _Pragma("unroll") for (int m = 0; m < 4; m++)                            \
      _Pragma("unroll") for (int n = 0; n < 2; n++)                          \
        _Pragma("unroll") for (int ks = 0; ks < 2; ks++)                     \
          acc[(MH)*4 + m][(NH)*2 + n] =                                      \
            mfma32h(bf[NH][n][ks], af[m][ks], acc[(MH)*4 + m][(NH)*2 + n]);  \
  } else {                                                                   \
    _Pragma("unroll") for (int m = 0; m < 4; m++)                            \
      _Pragma("unroll") for (int n = 0; n < 2; n++)                          \
        _Pragma("unroll") for (int ks = 0; ks < 2; ks++)                     \
          acc[(MH)*4 + m][(NH)*2 + n] =                                      \
            mfma32h(af[m][ks], bf[NH][n][ks], acc[(MH)*4 + m][(NH)*2 + n]);  \
  }                                                                          \
  __builtin_amdgcn_s_setprio(0)

#pragma unroll 2
  for (int t = 0; t < NKT; t++) {
    const unsigned short* Ac0 = &As[t & 1][0][0];
    const unsigned short* Ac1 = &As[t & 1][1][0];
    const unsigned short* Bcw = &Bs[t & 1][wx >> 1][0];   // wave's B half
    const int nb = (t + 1) & 1;
    f16x8 af[4][2], bf[2][2][2];

    // ---- phase 0: quadrant (mh0, nh0); 12 ds_reads ----
#pragma unroll
    for (int m = 0; m < 4; m++) {
      af[m][0] = ldfragh(Ac0 + ar + m * 1024 + sl0);
      af[m][1] = ldfragh(Ac0 + ar + m * 1024 + sl1);
    }
#pragma unroll
    for (int n = 0; n < 2; n++) {
      bf[0][n][0] = ldfragh(Bcw + br + n * 1024 + sl0);
      bf[0][n][1] = ldfragh(Bcw + br + n * 1024 + sl1);
    }
    if (t <= 10) STAGE(Bs[nb][1], B1G, t + 1);
    BAR(); LGKM0();
    MFMA_PHASE(0, 0);
    BAR();

    // ---- phase 1: quadrant (mh0, nh1); 4 ds_reads ----
#pragma unroll
    for (int n = 0; n < 2; n++) {
      bf[1][n][0] = ldfragh(Bcw + br + (2 + n) * 1024 + sl0);
      bf[1][n][1] = ldfragh(Bcw + br + (2 + n) * 1024 + sl1);
    }
    if (t <= 10) STAGE(As[nb][1], A1G, t + 1);
    if (t <= 10) { VMW(8); }
    else         { VMW(0); }
    BAR(); LGKM0();
    MFMA_PHASE(0, 1);
    BAR();

    // ---- phase 2: quadrant (mh1, nh0); 8 ds_reads ----
#pragma unroll
    for (int m = 0; m < 4; m++) {
      af[m][0] = ldfragh(Ac1 + ar + m * 1024 + sl0);
      af[m][1] = ldfragh(Ac1 + ar + m * 1024 + sl1);
    }
    if (t <= 9) STAGE(As[t & 1][0], A0G, t + 2);
    BAR(); LGKM0();
    MFMA_PHASE(1, 0);
    BAR();

    // ---- phase 3: quadrant (mh1, nh1); 0 ds_reads ----
    if (t <= 9) STAGE(Bs[t & 1][0], B0G, t + 2);
    if (t <= 9)       { VMW(6); }
    else if (t == 10) { VMW(2); }
    BAR();
    MFMA_PHASE(1, 1);
    BAR();
  }
#undef STAGE
#undef MFMA_PHASE

  if (MODE == 0) {
    if (swap) {
      // q/k (bn 0..5): reg dim = d, l15 = m
#pragma unroll
      for (int mi = 0; mi < 8; mi++) {
        int m = bm * 256 + (mi >> 2) * 128 + wy * 64 + (mi & 3) * 16 + l15;
#pragma unroll
        for (int ni = 0; ni < 4; ni++) {
          int d0 = bn * 256 + wx * 64 + (ni >> 1) * 32 + (ni & 1) * 16 + quad * 4;
          uint2 pk; pk.x = pkh(acc[mi][ni][0], acc[mi][ni][1]);
          pk.y = pkh(acc[mi][ni][2], acc[mi][ni][3]);
          *(uint2*)(out_hf + (long)m * C2 + d0) = pk;
        }
      }
    } else {
      // V (bn 6..8): reg dim = m(token), l15 = d -> vT(bp,h,e,n)
#pragma unroll
      for (int mi = 0; mi < 8; mi++) {
        int mg = bm * 256 + (mi >> 2) * 128 + wy * 64 + (mi & 3) * 16 + quad * 4;
        int bp = mg >> 9, n0 = mg & 511;
#pragma unroll
        for (int ni = 0; ni < 4; ni++) {
          int dp = (bn - 6) * 256 + wx * 64 + (ni >> 1) * 32 + (ni & 1) * 16 + l15;
          int hh = dp >> 6, e = dp & 63;
          uint2 pk; pk.x = pkh(acc[mi][ni][0], acc[mi][ni][1]);
          pk.y = pkh(acc[mi][ni][2], acc[mi][ni][3]);
          *(uint2*)(out_vT + ((long)((bp * 12 + hh) * 64 + e) * 512 + n0)) = pk;
        }
      }
    }
  } else {
    // proj: swapped, fp32 out + vec4 bias
#pragma unroll
    for (int ni = 0; ni < 4; ni++) {
      int d0 = bn * 256 + wx * 64 + (ni >> 1) * 32 + (ni & 1) * 16 + quad * 4;
      float4 bv = *(const float4*)(bias + d0);
#pragma unroll
      for (int mi = 0; mi < 8; mi++) {
        int m = bm * 256 + (mi >> 2) * 128 + wy * 64 + (mi & 3) * 16 + l15;
        float4 o;
        o.x = acc[mi][ni][0] + bv.x; o.y = acc[mi][ni][1] + bv.y;
        o.z = acc[mi][ni][2] + bv.z; o.w = acc[mi][ni][3] + bv.w;
        *(float4*)(out_f32 + (long)m * CDIM + d0) = o;
      }
    }
  }
}

// ---------- kernel 3: flash attention (S^T form), 1 block = (head, 128 Q rows) ----------
__global__ __launch_bounds__(256, 4) void attn_kernel(
    const unsigned short* __restrict__ qk, const unsigned short* __restrict__ vT,
    unsigned short* __restrict__ aout) {
  const int bph = blockIdx.x;
  const int qt  = blockIdx.y;
  const int bp = bph / 12, h = bph % 12;
  const int tid = threadIdx.x;
  const int wave = tid >> 6, lane = tid & 63;
  const int l15 = lane & 15, quad = lane >> 4;

  __shared__ unsigned short Qs[128 * 72];
  __shared__ unsigned short Ks[64 * 72];
  __shared__ unsigned short Vs[64 * 72];

  const unsigned short* Qg = qk + (long)(bp * 512 + qt * 128) * C2 + h * 64;
  const unsigned short* Kg = qk + (long)(bp * 512) * C2 + CDIM + h * 64;
  const unsigned short* Vg = vT + (long)(bp * 12 + h) * 64 * 512;

  for (int i = 0; i < 4; i++) {
    int c = tid + i * 256;
    int row = c >> 3, c8 = c & 7;
    *(uint4*)(Qs + row * 72 + c8 * 8) = *(const uint4*)(Qg + (long)row * C2 + c8 * 8);
  }

  f32x4 o[2][4];
  float lrow[2] = {0.f, 0.f};
  for (int a = 0; a < 2; a++)
    for (int b = 0; b < 4; b++) o[a][b] = f32x4{0.f, 0.f, 0.f, 0.f};

  for (int ch = 0; ch < 8; ch++) {
    if (ch) __syncthreads();
    for (int i = 0; i < 2; i++) {
      int c = tid + i * 256;
      int row = c >> 3, c8 = c & 7;
      *(uint4*)(Ks + row * 72 + c8 * 8) = *(const uint4*)(Kg + (long)(ch * 64 + row) * C2 + c8 * 8);
      *(uint4*)(Vs + row * 72 + c8 * 8) = *(const uint4*)(Vg + (long)row * 512 + ch * 64 + c8 * 8);
    }
    __syncthreads();

    f32x4 st[2][4];
    for (int a = 0; a < 2; a++)
      for (int b = 0; b < 4; b++) st[a][b] = f32x4{0.f, 0.f, 0.f, 0.f};
    for (int ks = 0; ks < 2; ks++) {
      f16x8 qf[2];
      qf[0] = ldfragh(Qs + (wave * 32 +      l15) * 72 + ks * 32 + quad * 8);
      qf[1] = ldfragh(Qs + (wave * 32 + 16 + l15) * 72 + ks * 32 + quad * 8);
      for (int nt = 0; nt < 4; nt++) {
        f16x8 kf = ldfragh(Ks + (nt * 16 + l15) * 72 + ks * 32 + quad * 8);
        st[0][nt] = mfma32h(kf, qf[0], st[0][nt]);
        st[1][nt] = mfma32h(kf, qf[1], st[1][nt]);
      }
    }

    f16x4 pf[2][4];
    for (int mt2 = 0; mt2 < 2; mt2++) {
      float rs = 0.f;
      for (int nt = 0; nt < 4; nt++) {
        f32x4 p;
        for (int r = 0; r < 4; r++) {
          p[r] = __builtin_amdgcn_exp2f(st[mt2][nt][r]);
          rs += p[r];
        }
        uint2 pk2; pk2.x = pkh(p[0], p[1]); pk2.y = pkh(p[2], p[3]);
        pf[mt2][nt] = __builtin_bit_cast(f16x4, pk2);
      }
      lrow[mt2] += rs;
    }

    for (int nt = 0; nt < 4; nt++)
      for (int et = 0; et < 4; et++) {
        f16x4 vf = ldfragh4(Vs + (et * 16 + l15) * 72 + nt * 16 + quad * 4);
        o[0][et] = mfma16h(vf, pf[0][nt], o[0][et]);
        o[1][et] = mfma16h(vf, pf[1][nt], o[1][et]);
      }
  }

  for (int mt2 = 0; mt2 < 2; mt2++) {
    float l = lrow[mt2];
    l += __shfl_xor(l, 16);
    l += __shfl_xor(l, 32);
    float inv = 1.f / l;
    int q = qt * 128 + wave * 32 + mt2 * 16 + l15;
    for (int et = 0; et < 4; et++) {
      uint2 pk; pk.x = pkh(o[mt2][et][0] * inv, o[mt2][et][1] * inv);
      pk.y = pkh(o[mt2][et][2] * inv, o[mt2][et][3] * inv);
      *(uint2*)(aout + (long)(bp * 512 + q) * CDIM + h * 64 + et * 16 + quad * 4) = pk;
    }
  }
}

// ---------- launch ----------
extern "C" void kernel_launch(void* const* d_in, const int* in_sizes, int n_in,
                              void* d_out, int out_size, void* d_ws, size_t ws_size,
                              hipStream_t stream) {
  (void)in_sizes; (void)n_in; (void)out_size; (void)ws_size;
  const float* x     = (const float*)d_in[0];
  const float* wqkv  = (const float*)d_in[1];
  const float* wproj = (const float*)d_in[2];
  const float* bproj = (const float*)d_in[3];
  float* out = (float*)d_out;
  char* ws = (char*)d_ws;

  unsigned short* xb     = (unsigned short*)(ws + XB_OFF);
  unsigned short* wqkvb  = (unsigned short*)(ws + WQKV_OFF);
  unsigned short* wprojb = (unsigned short*)(ws + WPROJ_OFF);
  unsigned short* qkbuf  = (unsigned short*)(ws + QK_OFF);
  unsigned short* vTbuf  = (unsigned short*)(ws + VT_OFF);
  unsigned short* attn_o = xb;

  convert_kernel<<<2048, 256, 0, stream>>>(x, wqkv, wproj, xb, wqkvb, wprojb);
  // QKV: 64 m-tiles x 9 n-tiles = 576 blocks (576 % 8 == 0)
  gemm256<0, 9><<<576, 512, 0, stream>>>(xb, wqkvb, qkbuf, vTbuf, nullptr, nullptr);
  attn_kernel<<<dim3(384, 4), 256, 0, stream>>>(qkbuf, vTbuf, attn_o);
  // proj: 64 x 3 = 192 blocks
  gemm256<2, 3><<<192, 512, 0, stream>>>(attn_o, wprojb, nullptr, nullptr, out, bproj);
}